// Round 12
// baseline (65.231 us; speedup 1.0000x reference)
//
#include <hip/hip_runtime.h>
#include <hip/hip_bf16.h>

typedef unsigned short u16;
typedef short bf16x8 __attribute__((ext_vector_type(8)));
typedef u16 u16x8 __attribute__((ext_vector_type(8)));
typedef u16 u16x4 __attribute__((ext_vector_type(4)));
typedef float f32x4 __attribute__((ext_vector_type(4)));
typedef unsigned u32x4 __attribute__((ext_vector_type(4)));

#define D_MODEL 512
#define L_SEQ 2048
#define B_SZ 4
#define N_HEADS 8
#define D_K 64
#define M_ROWS 8192
#define NQKV 1536
#define WIN 10

__device__ inline u16 f2bf(float x) {
  __hip_bfloat16 h = __float2bfloat16(x);
  return *reinterpret_cast<u16*>(&h);
}
__device__ inline float bf2f(u16 u) {
  __hip_bfloat16 h;
  *reinterpret_cast<u16*>(&h) = u;
  return __bfloat162float(h);
}
// packed f32 pair -> 2 bf16 (RNE, same as __float2bfloat16)
__device__ inline unsigned pk2(float lo, float hi) {
  __hip_bfloat162 r = __float22bfloat162_rn(float2{lo, hi});
  return *reinterpret_cast<unsigned*>(&r);
}

// async global->LDS, 16B/lane; LDS dest = WAVE-UNIFORM base + lane*16 (HW)
__device__ inline void stage16(const void* gptr, void* ldsptr) {
  void* g = const_cast<void*>(gptr);
  __builtin_amdgcn_global_load_lds(
      (__attribute__((address_space(1))) void*)g,
      (__attribute__((address_space(3))) void*)ldsptr, 16, 0, 0);
}

// =============== prep: pack_w(transposed, bf16) | bias (257 blocks) ===============
__global__ __launch_bounds__(256) void prep(
    const float* __restrict__ Wq, const float* __restrict__ Wk,
    const float* __restrict__ Wv, const float* __restrict__ Wo,
    const float* __restrict__ bq, const float* __restrict__ bk,
    const float* __restrict__ bv,
    u16* __restrict__ Bqkv, u16* __restrict__ Bo, float* __restrict__ bias_qkv) {
  __shared__ float wlds[64 * 65];
  int blk = blockIdx.x, t = threadIdx.x;
  if (blk < 256) {
    int which = blk >> 6;
    int t64 = blk & 63;
    int k0 = (t64 >> 3) * 64, n0 = (t64 & 7) * 64;
    const float* W = which == 0 ? Wq : which == 1 ? Wk : which == 2 ? Wv : Wo;
    int c = t & 63, g = t >> 6;
#pragma unroll
    for (int rr = 0; rr < 16; ++rr) {
      int kl = g * 16 + rr;
      wlds[kl * 65 + c] = W[(size_t)(k0 + kl) * 512 + n0 + c];
    }
    __syncthreads();
    u16* dst = which < 3 ? Bqkv : Bo;
    int nbase = which < 3 ? which * 512 : 0;
#pragma unroll
    for (int rr = 0; rr < 16; ++rr) {
      int nl = g * 16 + rr;
      float v = wlds[c * 65 + nl];
      dst[(size_t)(nbase + n0 + nl) * 512 + k0 + c] = f2bf(v);
    }
    return;
  }
  for (int i = t; i < 1536; i += 256)
    bias_qkv[i] = i < 512 ? bq[i] : i < 1024 ? bk[i - 512] : bv[i - 1024];
}

// ========== QKV GEMM: 128x128, BK=32, 2-phase dbuf; A = f32 X via gload_lds ==========
// A staged raw f32 (swizzled source granules, r5-verified bijection), converted
// to bf16 at frag-read time via v_cvt_pk_bf16_f32. B bf16 linear (as r10).
__global__ __launch_bounds__(256) void gemm_qkv(
    const float* __restrict__ X, const u16* __restrict__ B,
    const float* __restrict__ bias, u16* __restrict__ C) {
  __shared__ float sA[2][128 * 32];   // 16KB/buf, rows 128B = 8 granules
  __shared__ u16 sB[2][128 * 32];     // 8KB/buf
  int t = threadIdx.x, w = t >> 6, lane = t & 63;
  // XCD-bijective swizzle: 768 blocks (12 n x 64 m)
  int bid = blockIdx.y * 12 + blockIdx.x;
  int swz = (bid & 7) * 96 + (bid >> 3);
  long m0 = (long)(swz / 12) * 128, n0 = (long)(swz % 12) * 128;
  int wm = (w >> 1) * 64, wn = (w & 1) * 64;
  int fr = lane & 15, fo = lane >> 4;
  int rl = lane >> 2, cb = (lane & 3) * 16;
  const char* Bb = (const char*)B;

  int arl = lane >> 3;                   // row within 8-row chunk
  int asg = (lane & 7) ^ arl;            // swizzled source granule (16B units)

  f32x4 acc[4][4] = {};

#define STAGE_QKV(buf, kt)                                                  \
  do {                                                                      \
    _Pragma("unroll") for (int c = 0; c < 4; ++c) {                         \
      int ch = w + c * 4;                                                   \
      int row = ch * 8 + arl;                                               \
      stage16((const char*)(X + (m0 + row) * 512 + (long)(kt) * 32) +       \
                  asg * 16,                                                 \
              (char*)sA[buf] + ch * 1024);                                  \
    }                                                                       \
    int c0 = w, c1 = w + 4;                                                 \
    int r0 = c0 * 16 + rl, r1 = c1 * 16 + rl;                               \
    stage16(Bb + ((n0 + r0) * 512 + (long)(kt) * 32) * 2 + cb,              \
            (char*)sB[buf] + c0 * 1024);                                    \
    stage16(Bb + ((n0 + r1) * 512 + (long)(kt) * 32) * 2 + cb,              \
            (char*)sB[buf] + c1 * 1024);                                    \
  } while (0)

  STAGE_QKV(0, 0);
  __syncthreads();

  for (int kt = 0; kt < 16; ++kt) {
    int cur = kt & 1;
    if (kt < 15) STAGE_QKV(cur ^ 1, kt + 1);
    bf16x8 af[4], bf[4];
#pragma unroll
    for (int m = 0; m < 4; ++m) {
      int r = wm + m * 16 + fr;
      const char* rowp = (const char*)&sA[cur][r * 32];
      f32x4 a0 = *(const f32x4*)(rowp + (((fo * 2) ^ (fr & 7)) * 16));
      f32x4 a1 = *(const f32x4*)(rowp + (((fo * 2 + 1) ^ (fr & 7)) * 16));
      u32x4 pk;
      pk[0] = pk2(a0[0], a0[1]);
      pk[1] = pk2(a0[2], a0[3]);
      pk[2] = pk2(a1[0], a1[1]);
      pk[3] = pk2(a1[2], a1[3]);
      af[m] = *reinterpret_cast<bf16x8*>(&pk);
    }
#pragma unroll
    for (int n = 0; n < 4; ++n)
      bf[n] = *(const bf16x8*)&sB[cur][(wn + n * 16 + fr) * 32 + fo * 8];
#pragma unroll
    for (int m = 0; m < 4; ++m)
#pragma unroll
      for (int n = 0; n < 4; ++n)
        acc[m][n] = __builtin_amdgcn_mfma_f32_16x16x32_bf16(af[m], bf[n], acc[m][n], 0, 0, 0);
    __syncthreads();
  }
#undef STAGE_QKV

  int rbase = m0 + wm + fo * 4, cbase = n0 + wn + fr;
#pragma unroll
  for (int n = 0; n < 4; ++n) {
    int col = cbase + n * 16;
    float bn = bias[col];
#pragma unroll
    for (int m = 0; m < 4; ++m) {
      int row = rbase + m * 16;
#pragma unroll
      for (int q = 0; q < 4; ++q)
        C[(size_t)(row + q) * NQKV + col] = f2bf(acc[m][n][q] + bn);
    }
  }
}

// ========== O GEMM: 64x128 tile (512 blocks = 2/CU), BK=32, 2-phase dbuf ==========
__global__ __launch_bounds__(256) void gemm_o(
    const u16* __restrict__ A, const u16* __restrict__ B,
    const float* __restrict__ bias, float* __restrict__ C) {
  __shared__ u16 sA[2][64 * 32], sB[2][128 * 32];
  int t = threadIdx.x, w = t >> 6, lane = t & 63;
  int bid = blockIdx.y * 4 + blockIdx.x;
  int swz = (bid & 7) * 64 + (bid >> 3);
  long m0 = (long)(swz / 4) * 64, n0 = (long)(swz % 4) * 128;
  int wn = w * 32;
  int fr = lane & 15, fo = lane >> 4;
  int rl = lane >> 2, cb = (lane & 3) * 16;
  const char* Ab = (const char*)A;
  const char* Bb = (const char*)B;

  f32x4 acc[4][2] = {};

#define STAGE_O(buf, kt)                                                    \
  do {                                                                      \
    int ra = w * 16 + rl;                                                   \
    stage16(Ab + ((m0 + ra) * 512 + (long)(kt) * 32) * 2 + cb,              \
            (char*)sA[buf] + w * 1024);                                     \
    int c0 = w, c1 = w + 4;                                                 \
    int r0 = c0 * 16 + rl, r1 = c1 * 16 + rl;                               \
    stage16(Bb + ((n0 + r0) * 512 + (long)(kt) * 32) * 2 + cb,              \
            (char*)sB[buf] + c0 * 1024);                                    \
    stage16(Bb + ((n0 + r1) * 512 + (long)(kt) * 32) * 2 + cb,              \
            (char*)sB[buf] + c1 * 1024);                                    \
  } while (0)

  STAGE_O(0, 0);
  __syncthreads();

  for (int kt = 0; kt < 16; ++kt) {
    int cur = kt & 1;
    if (kt < 15) STAGE_O(cur ^ 1, kt + 1);
    bf16x8 af[4], bf[2];
#pragma unroll
    for (int m = 0; m < 4; ++m)
      af[m] = *(const bf16x8*)&sA[cur][(m * 16 + fr) * 32 + fo * 8];
#pragma unroll
    for (int n = 0; n < 2; ++n)
      bf[n] = *(const bf16x8*)&sB[cur][(wn + n * 16 + fr) * 32 + fo * 8];
#pragma unroll
    for (int m = 0; m < 4; ++m)
#pragma unroll
      for (int n = 0; n < 2; ++n)
        acc[m][n] = __builtin_amdgcn_mfma_f32_16x16x32_bf16(af[m], bf[n], acc[m][n], 0, 0, 0);
    __syncthreads();
  }
#undef STAGE_O

  int rbase = m0 + fo * 4, cbase = n0 + wn + fr;
#pragma unroll
  for (int n = 0; n < 2; ++n) {
    int col = cbase + n * 16;
    float bn = bias[col];
#pragma unroll
    for (int m = 0; m < 4; ++m) {
      int row = rbase + m * 16;
#pragma unroll
      for (int q = 0; q < 4; ++q)
        C[(size_t)(row + q) * 512 + col] = acc[m][n][q] + bn;
    }
  }
}

// ================= banded flash-attention on MFMA =================
#define ATTN_LDS 73216

__global__ __launch_bounds__(256) void attn_mfma(const u16* __restrict__ QKV,
                                                 u16* __restrict__ AOh) {
  extern __shared__ char lds[];
  u16* sQ = (u16*)lds;                     // [128][72]
  u16* sK = (u16*)(lds + 18432);           // [160][72]
  u16* sVT = (u16*)(lds + 41472);          // [64][176]
  int t = threadIdx.x, w = t >> 6, lane = t & 63;
  u16* sP = (u16*)(lds + 64000 + w * 2304);  // [16][72] wave-private

  int blk = blockIdx.x;
  int tile = blk & 15, h = (blk >> 4) & 7, b = blk >> 7;
  int l0 = tile * 128;
  const u16* base = QKV + (size_t)b * L_SEQ * NQKV + h * D_K;

#pragma unroll
  for (int i = 0; i < 4; ++i) {
    int task = t + i * 256;
    int row = task >> 3, oct = task & 7;
    u16x8 g = *(const u16x8*)(base + (size_t)(l0 + row) * NQKV + oct * 8);
    *(u16x8*)(sQ + row * 72 + oct * 8) = g;
  }
#pragma unroll
  for (int i = 0; i < 5; ++i) {
    int task = t + i * 256;
    int row = task >> 3, oct = task & 7;
    int l = min(max(l0 - 16 + row, 0), L_SEQ - 1);
    u16x8 g = *(const u16x8*)(base + (size_t)l * NQKV + 512 + oct * 8);
    *(u16x8*)(sK + row * 72 + oct * 8) = g;
  }
#pragma unroll
  for (int i = 0; i < 5; ++i) {
    int task = t + i * 256;
    int kv = task >> 3, oct = task & 7;
    int l = min(max(l0 - 16 + kv, 0), L_SEQ - 1);
    u16x8 g = *(const u16x8*)(base + (size_t)l * NQKV + 1024 + oct * 8);
#pragma unroll
    for (int e = 0; e < 8; ++e)
      sVT[(oct * 8 + e) * 176 + kv] = g[e];
  }
  if (t < 128) {
    u16x8 z = {};
    *(u16x8*)(sVT + (t >> 1) * 176 + 160 + (t & 1) * 8) = z;
  }
  if (lane < 32) {
    u16x8 z = {};
    *(u16x8*)(sP + (lane >> 1) * 72 + 48 + (lane & 1) * 8) = z;
  }
  __syncthreads();

  int fr = lane & 15, fo = lane >> 4;

  for (int qi = 0; qi < 2; ++qi) {
    if (qi) __syncthreads();
    int qt = w * 2 + qi;

    bf16x8 Aq[2];
#pragma unroll
    for (int ks = 0; ks < 2; ++ks)
      Aq[ks] = *(const bf16x8*)(sQ + (qt * 16 + fr) * 72 + ks * 32 + fo * 8);

    f32x4 sc[3] = {};
#pragma unroll
    for (int kt = 0; kt < 3; ++kt)
#pragma unroll
      for (int ks = 0; ks < 2; ++ks) {
        bf16x8 Bk = *(const bf16x8*)(sK + (qt * 16 + kt * 16 + fr) * 72 + ks * 32 + fo * 8);
        sc[kt] = __builtin_amdgcn_mfma_f32_16x16x32_bf16(Aq[ks], Bk, sc[kt], 0, 0, 0);
      }

    float pj[3][4], mj[4], rj[4];
#pragma unroll
    for (int j = 0; j < 4; ++j) {
      int irow = l0 + qt * 16 + fo * 4 + j;
      float mloc = -1.0e30f;
#pragma unroll
      for (int kt = 0; kt < 3; ++kt) {
        int jcol = l0 - 16 + qt * 16 + kt * 16 + fr;
        float sv = fminf(fmaxf(sc[kt][j] * 0.125f, -10000.f), 10000.f);
        int dd = irow - jcol;
        bool ok = (dd <= WIN) && (dd >= -WIN) && (jcol >= 0) && (jcol < L_SEQ);
        sv = ok ? sv : -1.0e30f;
        pj[kt][j] = sv;
        mloc = fmaxf(mloc, sv);
      }
      mj[j] = mloc;
    }
#pragma unroll
    for (int st = 1; st <= 8; st <<= 1)
#pragma unroll
      for (int j = 0; j < 4; ++j)
        mj[j] = fmaxf(mj[j], __shfl_xor(mj[j], st));
#pragma unroll
    for (int j = 0; j < 4; ++j) {
      float r = 0.f;
#pragma unroll
      for (int kt = 0; kt < 3; ++kt) {
        float e = (pj[kt][j] > -1.0e29f) ? __expf(pj[kt][j] - mj[j]) : 0.f;
        pj[kt][j] = e;
        r += e;
      }
      rj[j] = r;
    }
#pragma unroll
    for (int st = 1; st <= 8; st <<= 1)
#pragma unroll
      for (int j = 0; j < 4; ++j)
        rj[j] += __shfl_xor(rj[j], st);
#pragma unroll
    for (int j = 0; j < 4; ++j) rj[j] = 1.f / rj[j];

#pragma unroll
    for (int kt = 0; kt < 3; ++kt)
#pragma unroll
      for (int j = 0; j < 4; ++j)
        sP[(fo * 4 + j) * 72 + kt * 16 + fr] = f2bf(pj[kt][j] * rj[j]);

    f32x4 oa[4] = {};
#pragma unroll
    for (int ks = 0; ks < 2; ++ks) {
      bf16x8 Ap = *(const bf16x8*)(sP + fr * 72 + ks * 32 + fo * 8);
#pragma unroll
      for (int nt = 0; nt < 4; ++nt) {
        bf16x8 Bv = *(const bf16x8*)(sVT + (nt * 16 + fr) * 176 + qt * 16 + ks * 32 + fo * 8);
        oa[nt] = __builtin_amdgcn_mfma_f32_16x16x32_bf16(Ap, Bv, oa[nt], 0, 0, 0);
      }
    }

#pragma unroll
    for (int nt = 0; nt < 4; ++nt)
#pragma unroll
      for (int j = 0; j < 4; ++j) {
        size_t row = (size_t)b * L_SEQ + l0 + qt * 16 + fo * 4 + j;
        AOh[row * D_MODEL + h * D_K + nt * 16 + fr] = f2bf(oa[nt][j]);
      }
  }
}

extern "C" void kernel_launch(void* const* d_in, const int* in_sizes, int n_in,
                              void* d_out, int out_size, void* d_ws, size_t ws_size,
                              hipStream_t stream) {
  const float* Q  = (const float*)d_in[0];
  const float* Wq = (const float*)d_in[1];
  const float* bq = (const float*)d_in[2];
  const float* Wk = (const float*)d_in[3];
  const float* bk = (const float*)d_in[4];
  const float* Wv = (const float*)d_in[5];
  const float* bv = (const float*)d_in[6];
  const float* Wo = (const float*)d_in[7];
  const float* bo = (const float*)d_in[8];
  float* out = (float*)d_out;

  char* p = (char*)d_ws;
  u16* Bqkv = (u16*)p;      p += (size_t)1536 * 512 * 2;
  u16* Bo = (u16*)p;        p += (size_t)512 * 512 * 2;
  float* bias_qkv = (float*)p; p += 1536 * 4;
  u16* QKV = (u16*)p;       p += (size_t)M_ROWS * 1536 * 2;
  u16* AOh = (u16*)p;       p += (size_t)M_ROWS * 512 * 2;

  hipFuncSetAttribute((const void*)attn_mfma,
                      hipFuncAttributeMaxDynamicSharedMemorySize, ATTN_LDS);

  hipLaunchKernelGGL(prep, dim3(257), dim3(256), 0, stream,
                     Wq, Wk, Wv, Wo, bq, bk, bv, Bqkv, Bo, bias_qkv);

  // QKV: 12 n-tiles x 64 m-tiles = 768 blocks; A = f32 X, converted in-kernel
  gemm_qkv<<<dim3(12, 64), dim3(256), 0, stream>>>(Q, Bqkv, bias_qkv, QKV);

  // attn: (b, h, tile) = 4*8*16 = 512 blocks (2/CU)
  hipLaunchKernelGGL(attn_mfma, dim3(512), dim3(256), ATTN_LDS, stream, QKV, AOh);

  // O: 4 n-tiles x 128 m-tiles = 512 blocks (2/CU)
  gemm_o<<<dim3(4, 128), dim3(256), 0, stream>>>(AOh, Bo, bo, out);
}

// Round 13
// 62.188 us; speedup vs baseline: 1.0489x; 1.0489x over previous
//
#include <hip/hip_runtime.h>
#include <hip/hip_bf16.h>

typedef unsigned short u16;
typedef short bf16x8 __attribute__((ext_vector_type(8)));
typedef u16 u16x8 __attribute__((ext_vector_type(8)));
typedef u16 u16x4 __attribute__((ext_vector_type(4)));
typedef float f32x4 __attribute__((ext_vector_type(4)));

#define D_MODEL 512
#define L_SEQ 2048
#define B_SZ 4
#define N_HEADS 8
#define D_K 64
#define M_ROWS 8192
#define NQKV 1536
#define WIN 10

__device__ inline u16 f2bf(float x) {
  __hip_bfloat16 h = __float2bfloat16(x);
  return *reinterpret_cast<u16*>(&h);
}
__device__ inline float bf2f(u16 u) {
  __hip_bfloat16 h;
  *reinterpret_cast<u16*>(&h) = u;
  return __bfloat162float(h);
}

// async global->LDS, 16B/lane; LDS dest = WAVE-UNIFORM base + lane*16 (HW)
__device__ inline void stage16(const void* gptr, void* ldsptr) {
  void* g = const_cast<void*>(gptr);
  __builtin_amdgcn_global_load_lds(
      (__attribute__((address_space(1))) void*)g,
      (__attribute__((address_space(3))) void*)ldsptr, 16, 0, 0);
}

// =============== fused prep: pack_x | pack_w(transposed, bf16) | bias ===============
__global__ __launch_bounds__(256) void prep(
    const float* __restrict__ X, const float* __restrict__ Wq,
    const float* __restrict__ Wk, const float* __restrict__ Wv,
    const float* __restrict__ Wo, const float* __restrict__ bq,
    const float* __restrict__ bk, const float* __restrict__ bv,
    u16* __restrict__ Xh, u16* __restrict__ Bqkv, u16* __restrict__ Bo,
    float* __restrict__ bias_qkv) {
  __shared__ float wlds[64 * 65];
  int blk = blockIdx.x, t = threadIdx.x;
  if (blk < 4096) {
    int i = blk * 256 + t;
    float4 x = ((const float4*)X)[i];
    u16x4 o;
    o[0] = f2bf(x.x); o[1] = f2bf(x.y); o[2] = f2bf(x.z); o[3] = f2bf(x.w);
    *(u16x4*)(Xh + i * 4) = o;
    return;
  }
  if (blk < 4352) {
    int tid = blk - 4096;
    int which = tid >> 6;
    int t64 = tid & 63;
    int k0 = (t64 >> 3) * 64, n0 = (t64 & 7) * 64;
    const float* W = which == 0 ? Wq : which == 1 ? Wk : which == 2 ? Wv : Wo;
    int c = t & 63, g = t >> 6;
#pragma unroll
    for (int rr = 0; rr < 16; ++rr) {
      int kl = g * 16 + rr;
      wlds[kl * 65 + c] = W[(size_t)(k0 + kl) * 512 + n0 + c];
    }
    __syncthreads();
    u16* dst = which < 3 ? Bqkv : Bo;
    int nbase = which < 3 ? which * 512 : 0;
#pragma unroll
    for (int rr = 0; rr < 16; ++rr) {
      int nl = g * 16 + rr;
      float v = wlds[c * 65 + nl];
      dst[(size_t)(nbase + n0 + nl) * 512 + k0 + c] = f2bf(v);
    }
    return;
  }
  for (int i = t; i < 1536; i += 256)
    bias_qkv[i] = i < 512 ? bq[i] : i < 1024 ? bk[i - 512] : bv[i - 1024];
}

// ========== QKV GEMM: 128x128 tile, BK=64 (8 iters), 2-phase dbuf ==========
// Row = 128B in LDS -> XOR-swizzle both sides (rule 21): source granule
// (lane&7)^(row&7) at stage time, read slot (ks*4+fo)^(row&7). 2-way banks.
__global__ __launch_bounds__(256) void gemm_qkv(
    const u16* __restrict__ A, const u16* __restrict__ B,
    const float* __restrict__ bias, u16* __restrict__ C) {
  __shared__ u16 sA[2][128 * 64], sB[2][128 * 64];  // 64KB total
  int t = threadIdx.x, w = t >> 6, lane = t & 63;
  // XCD-bijective swizzle: 768 blocks (12 n x 64 m)
  int bid = blockIdx.y * 12 + blockIdx.x;
  int swz = (bid & 7) * 96 + (bid >> 3);
  long m0 = (long)(swz / 12) * 128, n0 = (long)(swz % 12) * 128;
  int wm = (w >> 1) * 64, wn = (w & 1) * 64;
  int fr = lane & 15, fo = lane >> 4;
  int rl8 = lane >> 3;                 // row within 8-row chunk
  int sg = (lane & 7) ^ (rl8 & 7);     // swizzled source granule (16B)
  const char* Ab = (const char*)A;
  const char* Bb = (const char*)B;

  f32x4 acc[4][4] = {};

  // 16 chunks of 1KB (8 rows x 128B) per array; 4 chunks/wave/array
#define STAGE_QKV(buf, kt)                                                  \
  do {                                                                      \
    _Pragma("unroll") for (int c = 0; c < 4; ++c) {                         \
      int ch = w * 4 + c;                                                   \
      int row = ch * 8 + rl8;                                               \
      stage16(Ab + ((m0 + row) * 512 + (long)(kt) * 64) * 2 + sg * 16,      \
              (char*)sA[buf] + ch * 1024);                                  \
      stage16(Bb + ((n0 + row) * 512 + (long)(kt) * 64) * 2 + sg * 16,      \
              (char*)sB[buf] + ch * 1024);                                  \
    }                                                                       \
  } while (0)

  STAGE_QKV(0, 0);
  __syncthreads();

  for (int kt = 0; kt < 8; ++kt) {
    int cur = kt & 1;
    if (kt < 7) STAGE_QKV(cur ^ 1, kt + 1);
    bf16x8 af[4][2], bf[4][2];
#pragma unroll
    for (int m = 0; m < 4; ++m) {
      int r = wm + m * 16 + fr;
#pragma unroll
      for (int ks = 0; ks < 2; ++ks)
        af[m][ks] = *(const bf16x8*)&sA[cur][r * 64 + (((ks * 4 + fo) ^ (r & 7)) * 8)];
    }
#pragma unroll
    for (int n = 0; n < 4; ++n) {
      int r = wn + n * 16 + fr;
#pragma unroll
      for (int ks = 0; ks < 2; ++ks)
        bf[n][ks] = *(const bf16x8*)&sB[cur][r * 64 + (((ks * 4 + fo) ^ (r & 7)) * 8)];
    }
#pragma unroll
    for (int m = 0; m < 4; ++m)
#pragma unroll
      for (int n = 0; n < 4; ++n)
#pragma unroll
        for (int ks = 0; ks < 2; ++ks)
          acc[m][n] = __builtin_amdgcn_mfma_f32_16x16x32_bf16(af[m][ks], bf[n][ks], acc[m][n], 0, 0, 0);
    __syncthreads();
  }
#undef STAGE_QKV

  int rbase = m0 + wm + fo * 4, cbase = n0 + wn + fr;
#pragma unroll
  for (int n = 0; n < 4; ++n) {
    int col = cbase + n * 16;
    float bn = bias[col];
#pragma unroll
    for (int m = 0; m < 4; ++m) {
      int row = rbase + m * 16;
#pragma unroll
      for (int q = 0; q < 4; ++q)
        C[(size_t)(row + q) * NQKV + col] = f2bf(acc[m][n][q] + bn);
    }
  }
}

// ========== O GEMM: 64x128 tile, BK=64 (8 iters), 2-phase dbuf ==========
__global__ __launch_bounds__(256) void gemm_o(
    const u16* __restrict__ A, const u16* __restrict__ B,
    const float* __restrict__ bias, float* __restrict__ C) {
  __shared__ u16 sA[2][64 * 64], sB[2][128 * 64];  // 48KB
  int t = threadIdx.x, w = t >> 6, lane = t & 63;
  int bid = blockIdx.y * 4 + blockIdx.x;
  int swz = (bid & 7) * 64 + (bid >> 3);
  long m0 = (long)(swz / 4) * 64, n0 = (long)(swz % 4) * 128;
  int wn = w * 32;
  int fr = lane & 15, fo = lane >> 4;
  int rl8 = lane >> 3;
  int sg = (lane & 7) ^ (rl8 & 7);
  const char* Ab = (const char*)A;
  const char* Bb = (const char*)B;

  f32x4 acc[4][2] = {};

  // A: 8 chunks (2/wave); B: 16 chunks (4/wave)
#define STAGE_O(buf, kt)                                                    \
  do {                                                                      \
    _Pragma("unroll") for (int c = 0; c < 2; ++c) {                         \
      int ch = w * 2 + c;                                                   \
      int row = ch * 8 + rl8;                                               \
      stage16(Ab + ((m0 + row) * 512 + (long)(kt) * 64) * 2 + sg * 16,      \
              (char*)sA[buf] + ch * 1024);                                  \
    }                                                                       \
    _Pragma("unroll") for (int c = 0; c < 4; ++c) {                         \
      int ch = w * 4 + c;                                                   \
      int row = ch * 8 + rl8;                                               \
      stage16(Bb + ((n0 + row) * 512 + (long)(kt) * 64) * 2 + sg * 16,      \
              (char*)sB[buf] + ch * 1024);                                  \
    }                                                                       \
  } while (0)

  STAGE_O(0, 0);
  __syncthreads();

  for (int kt = 0; kt < 8; ++kt) {
    int cur = kt & 1;
    if (kt < 7) STAGE_O(cur ^ 1, kt + 1);
    bf16x8 af[4][2], bf[2][2];
#pragma unroll
    for (int m = 0; m < 4; ++m) {
      int r = m * 16 + fr;
#pragma unroll
      for (int ks = 0; ks < 2; ++ks)
        af[m][ks] = *(const bf16x8*)&sA[cur][r * 64 + (((ks * 4 + fo) ^ (r & 7)) * 8)];
    }
#pragma unroll
    for (int n = 0; n < 2; ++n) {
      int r = wn + n * 16 + fr;
#pragma unroll
      for (int ks = 0; ks < 2; ++ks)
        bf[n][ks] = *(const bf16x8*)&sB[cur][r * 64 + (((ks * 4 + fo) ^ (r & 7)) * 8)];
    }
#pragma unroll
    for (int m = 0; m < 4; ++m)
#pragma unroll
      for (int n = 0; n < 2; ++n)
#pragma unroll
        for (int ks = 0; ks < 2; ++ks)
          acc[m][n] = __builtin_amdgcn_mfma_f32_16x16x32_bf16(af[m][ks], bf[n][ks], acc[m][n], 0, 0, 0);
    __syncthreads();
  }
#undef STAGE_O

  int rbase = m0 + fo * 4, cbase = n0 + wn + fr;
#pragma unroll
  for (int n = 0; n < 2; ++n) {
    int col = cbase + n * 16;
    float bn = bias[col];
#pragma unroll
    for (int m = 0; m < 4; ++m) {
      int row = rbase + m * 16;
#pragma unroll
      for (int q = 0; q < 4; ++q)
        C[(size_t)(row + q) * 512 + col] = acc[m][n][q] + bn;
    }
  }
}

// ================= banded flash-attention on MFMA (r10-identical) =================
#define ATTN_LDS 73216

__global__ __launch_bounds__(256) void attn_mfma(const u16* __restrict__ QKV,
                                                 u16* __restrict__ AOh) {
  extern __shared__ char lds[];
  u16* sQ = (u16*)lds;                     // [128][72]
  u16* sK = (u16*)(lds + 18432);           // [160][72]
  u16* sVT = (u16*)(lds + 41472);          // [64][176]
  int t = threadIdx.x, w = t >> 6, lane = t & 63;
  u16* sP = (u16*)(lds + 64000 + w * 2304);  // [16][72] wave-private

  int blk = blockIdx.x;
  int tile = blk & 15, h = (blk >> 4) & 7, b = blk >> 7;
  int l0 = tile * 128;
  const u16* base = QKV + (size_t)b * L_SEQ * NQKV + h * D_K;

#pragma unroll
  for (int i = 0; i < 4; ++i) {
    int task = t + i * 256;
    int row = task >> 3, oct = task & 7;
    u16x8 g = *(const u16x8*)(base + (size_t)(l0 + row) * NQKV + oct * 8);
    *(u16x8*)(sQ + row * 72 + oct * 8) = g;
  }
#pragma unroll
  for (int i = 0; i < 5; ++i) {
    int task = t + i * 256;
    int row = task >> 3, oct = task & 7;
    int l = min(max(l0 - 16 + row, 0), L_SEQ - 1);
    u16x8 g = *(const u16x8*)(base + (size_t)l * NQKV + 512 + oct * 8);
    *(u16x8*)(sK + row * 72 + oct * 8) = g;
  }
#pragma unroll
  for (int i = 0; i < 5; ++i) {
    int task = t + i * 256;
    int kv = task >> 3, oct = task & 7;
    int l = min(max(l0 - 16 + kv, 0), L_SEQ - 1);
    u16x8 g = *(const u16x8*)(base + (size_t)l * NQKV + 1024 + oct * 8);
#pragma unroll
    for (int e = 0; e < 8; ++e)
      sVT[(oct * 8 + e) * 176 + kv] = g[e];
  }
  if (t < 128) {
    u16x8 z = {};
    *(u16x8*)(sVT + (t >> 1) * 176 + 160 + (t & 1) * 8) = z;
  }
  if (lane < 32) {
    u16x8 z = {};
    *(u16x8*)(sP + (lane >> 1) * 72 + 48 + (lane & 1) * 8) = z;
  }
  __syncthreads();

  int fr = lane & 15, fo = lane >> 4;

  for (int qi = 0; qi < 2; ++qi) {
    if (qi) __syncthreads();
    int qt = w * 2 + qi;

    bf16x8 Aq[2];
#pragma unroll
    for (int ks = 0; ks < 2; ++ks)
      Aq[ks] = *(const bf16x8*)(sQ + (qt * 16 + fr) * 72 + ks * 32 + fo * 8);

    f32x4 sc[3] = {};
#pragma unroll
    for (int kt = 0; kt < 3; ++kt)
#pragma unroll
      for (int ks = 0; ks < 2; ++ks) {
        bf16x8 Bk = *(const bf16x8*)(sK + (qt * 16 + kt * 16 + fr) * 72 + ks * 32 + fo * 8);
        sc[kt] = __builtin_amdgcn_mfma_f32_16x16x32_bf16(Aq[ks], Bk, sc[kt], 0, 0, 0);
      }

    float pj[3][4], mj[4], rj[4];
#pragma unroll
    for (int j = 0; j < 4; ++j) {
      int irow = l0 + qt * 16 + fo * 4 + j;
      float mloc = -1.0e30f;
#pragma unroll
      for (int kt = 0; kt < 3; ++kt) {
        int jcol = l0 - 16 + qt * 16 + kt * 16 + fr;
        float sv = fminf(fmaxf(sc[kt][j] * 0.125f, -10000.f), 10000.f);
        int dd = irow - jcol;
        bool ok = (dd <= WIN) && (dd >= -WIN) && (jcol >= 0) && (jcol < L_SEQ);
        sv = ok ? sv : -1.0e30f;
        pj[kt][j] = sv;
        mloc = fmaxf(mloc, sv);
      }
      mj[j] = mloc;
    }
#pragma unroll
    for (int st = 1; st <= 8; st <<= 1)
#pragma unroll
      for (int j = 0; j < 4; ++j)
        mj[j] = fmaxf(mj[j], __shfl_xor(mj[j], st));
#pragma unroll
    for (int j = 0; j < 4; ++j) {
      float r = 0.f;
#pragma unroll
      for (int kt = 0; kt < 3; ++kt) {
        float e = (pj[kt][j] > -1.0e29f) ? __expf(pj[kt][j] - mj[j]) : 0.f;
        pj[kt][j] = e;
        r += e;
      }
      rj[j] = r;
    }
#pragma unroll
    for (int st = 1; st <= 8; st <<= 1)
#pragma unroll
      for (int j = 0; j < 4; ++j)
        rj[j] += __shfl_xor(rj[j], st);
#pragma unroll
    for (int j = 0; j < 4; ++j) rj[j] = 1.f / rj[j];

#pragma unroll
    for (int kt = 0; kt < 3; ++kt)
#pragma unroll
      for (int j = 0; j < 4; ++j)
        sP[(fo * 4 + j) * 72 + kt * 16 + fr] = f2bf(pj[kt][j] * rj[j]);

    f32x4 oa[4] = {};
#pragma unroll
    for (int ks = 0; ks < 2; ++ks) {
      bf16x8 Ap = *(const bf16x8*)(sP + fr * 72 + ks * 32 + fo * 8);
#pragma unroll
      for (int nt = 0; nt < 4; ++nt) {
        bf16x8 Bv = *(const bf16x8*)(sVT + (nt * 16 + fr) * 176 + qt * 16 + ks * 32 + fo * 8);
        oa[nt] = __builtin_amdgcn_mfma_f32_16x16x32_bf16(Ap, Bv, oa[nt], 0, 0, 0);
      }
    }

#pragma unroll
    for (int nt = 0; nt < 4; ++nt)
#pragma unroll
      for (int j = 0; j < 4; ++j) {
        size_t row = (size_t)b * L_SEQ + l0 + qt * 16 + fo * 4 + j;
        AOh[row * D_MODEL + h * D_K + nt * 16 + fr] = f2bf(oa[nt][j]);
      }
  }
}

extern "C" void kernel_launch(void* const* d_in, const int* in_sizes, int n_in,
                              void* d_out, int out_size, void* d_ws, size_t ws_size,
                              hipStream_t stream) {
  const float* Q  = (const float*)d_in[0];
  const float* Wq = (const float*)d_in[1];
  const float* bq = (const float*)d_in[2];
  const float* Wk = (const float*)d_in[3];
  const float* bk = (const float*)d_in[4];
  const float* Wv = (const float*)d_in[5];
  const float* bv = (const float*)d_in[6];
  const float* Wo = (const float*)d_in[7];
  const float* bo = (const float*)d_in[8];
  float* out = (float*)d_out;

  char* p = (char*)d_ws;
  u16* Xh = (u16*)p;        p += (size_t)M_ROWS * 512 * 2;
  u16* Bqkv = (u16*)p;      p += (size_t)1536 * 512 * 2;
  u16* Bo = (u16*)p;        p += (size_t)512 * 512 * 2;
  float* bias_qkv = (float*)p; p += 1536 * 4;
  u16* QKV = (u16*)p;       p += (size_t)M_ROWS * 1536 * 2;
  u16* AOh = (u16*)p;       p += (size_t)M_ROWS * 512 * 2;

  hipFuncSetAttribute((const void*)attn_mfma,
                      hipFuncAttributeMaxDynamicSharedMemorySize, ATTN_LDS);

  hipLaunchKernelGGL(prep, dim3(4353), dim3(256), 0, stream,
                     Q, Wq, Wk, Wv, Wo, bq, bk, bv, Xh, Bqkv, Bo, bias_qkv);

  // QKV: 12 n-tiles x 64 m-tiles = 768 blocks
  gemm_qkv<<<dim3(12, 64), dim3(256), 0, stream>>>(Xh, Bqkv, bias_qkv, QKV);

  // attn: (b, h, tile) = 4*8*16 = 512 blocks (2/CU)
  hipLaunchKernelGGL(attn_mfma, dim3(512), dim3(256), ATTN_LDS, stream, QKV, AOh);

  // O: 4 n-tiles x 128 m-tiles = 512 blocks
  gemm_o<<<dim3(4, 128), dim3(256), 0, stream>>>(AOh, Bo, bo, out);
}

// Round 14
// 55.393 us; speedup vs baseline: 1.1776x; 1.1227x over previous
//
#include <hip/hip_runtime.h>
#include <hip/hip_bf16.h>

typedef unsigned short u16;
typedef short bf16x8 __attribute__((ext_vector_type(8)));
typedef u16 u16x8 __attribute__((ext_vector_type(8)));
typedef u16 u16x4 __attribute__((ext_vector_type(4)));
typedef float f32x4 __attribute__((ext_vector_type(4)));

#define D_MODEL 512
#define L_SEQ 2048
#define B_SZ 4
#define N_HEADS 8
#define D_K 64
#define M_ROWS 8192
#define NQKV 1536
#define WIN 10

__device__ inline u16 f2bf(float x) {
  __hip_bfloat16 h = __float2bfloat16(x);
  return *reinterpret_cast<u16*>(&h);
}
__device__ inline float bf2f(u16 u) {
  __hip_bfloat16 h;
  *reinterpret_cast<u16*>(&h) = u;
  return __bfloat162float(h);
}

// async global->LDS, 16B/lane; LDS dest = WAVE-UNIFORM base + lane*16 (HW)
__device__ inline void stage16(const void* gptr, void* ldsptr) {
  void* g = const_cast<void*>(gptr);
  __builtin_amdgcn_global_load_lds(
      (__attribute__((address_space(1))) void*)g,
      (__attribute__((address_space(3))) void*)ldsptr, 16, 0, 0);
}

template <int N>
__device__ inline void vmwait() {
  asm volatile("s_waitcnt vmcnt(%0)" ::"i"(N) : "memory");
}
__device__ inline void lgkm0() {
  asm volatile("s_waitcnt lgkmcnt(0)" ::: "memory");
}
#define BARX()                      \
  do {                              \
    asm volatile("" ::: "memory");  \
    __builtin_amdgcn_s_barrier();   \
    asm volatile("" ::: "memory");  \
  } while (0)

// =============== fused prep: pack_x | pack_w(transposed, bf16) | bias ===============
__global__ __launch_bounds__(256) void prep(
    const float* __restrict__ X, const float* __restrict__ Wq,
    const float* __restrict__ Wk, const float* __restrict__ Wv,
    const float* __restrict__ Wo, const float* __restrict__ bq,
    const float* __restrict__ bk, const float* __restrict__ bv,
    u16* __restrict__ Xh, u16* __restrict__ Bqkv, u16* __restrict__ Bo,
    float* __restrict__ bias_qkv) {
  __shared__ float wlds[64 * 65];
  int blk = blockIdx.x, t = threadIdx.x;
  if (blk < 4096) {
    int i = blk * 256 + t;
    float4 x = ((const float4*)X)[i];
    u16x4 o;
    o[0] = f2bf(x.x); o[1] = f2bf(x.y); o[2] = f2bf(x.z); o[3] = f2bf(x.w);
    *(u16x4*)(Xh + i * 4) = o;
    return;
  }
  if (blk < 4352) {
    int tid = blk - 4096;
    int which = tid >> 6;
    int t64 = tid & 63;
    int k0 = (t64 >> 3) * 64, n0 = (t64 & 7) * 64;
    const float* W = which == 0 ? Wq : which == 1 ? Wk : which == 2 ? Wv : Wo;
    int c = t & 63, g = t >> 6;
#pragma unroll
    for (int rr = 0; rr < 16; ++rr) {
      int kl = g * 16 + rr;
      wlds[kl * 65 + c] = W[(size_t)(k0 + kl) * 512 + n0 + c];
    }
    __syncthreads();
    u16* dst = which < 3 ? Bqkv : Bo;
    int nbase = which < 3 ? which * 512 : 0;
#pragma unroll
    for (int rr = 0; rr < 16; ++rr) {
      int nl = g * 16 + rr;
      float v = wlds[c * 65 + nl];
      dst[(size_t)(nbase + n0 + nl) * 512 + k0 + c] = f2bf(v);
    }
    return;
  }
  for (int i = t; i < 1536; i += 256)
    bias_qkv[i] = i < 512 ? bq[i] : i < 1024 ? bk[i - 512] : bv[i - 1024];
}

// ========== QKV GEMM: 128x128, BK=32, TRIPLE-buffer counted-vmcnt pipeline ==========
// Per iter: vmcnt(4) proves stage(kt) done (this wave); raw barrier extends to all
// waves; lgkmcnt(0) before barrier protects buf being overwritten by stage(kt+2).
// Loads never drain to 0 in steady state (8 in flight, wait at 4).
__global__ __launch_bounds__(256) void gemm_qkv(
    const u16* __restrict__ A, const u16* __restrict__ B,
    const float* __restrict__ bias, u16* __restrict__ C) {
  __shared__ u16 sA[3][128 * 32], sB[3][128 * 32];  // 48KB
  int t = threadIdx.x, w = t >> 6, lane = t & 63;
  // XCD-bijective swizzle: 768 blocks (12 n x 64 m)
  int bid = blockIdx.y * 12 + blockIdx.x;
  int swz = (bid & 7) * 96 + (bid >> 3);
  long m0 = (long)(swz / 12) * 128, n0 = (long)(swz % 12) * 128;
  int wm = (w >> 1) * 64, wn = (w & 1) * 64;
  int fr = lane & 15, fo = lane >> 4;
  int rl = lane >> 2, cb = (lane & 3) * 16;
  const char* Ab = (const char*)A;
  const char* Bb = (const char*)B;

  f32x4 acc[4][4] = {};

  // 4 VMEM insts per thread per stage (A x2, B x2)
#define STAGE_QKV(buf, kt)                                                  \
  do {                                                                      \
    int c0 = w, c1 = w + 4;                                                 \
    int r0 = c0 * 16 + rl, r1 = c1 * 16 + rl;                               \
    stage16(Ab + ((m0 + r0) * 512 + (long)(kt) * 32) * 2 + cb,              \
            (char*)sA[buf] + c0 * 1024);                                    \
    stage16(Bb + ((n0 + r0) * 512 + (long)(kt) * 32) * 2 + cb,              \
            (char*)sB[buf] + c0 * 1024);                                    \
    stage16(Ab + ((m0 + r1) * 512 + (long)(kt) * 32) * 2 + cb,              \
            (char*)sA[buf] + c1 * 1024);                                    \
    stage16(Bb + ((n0 + r1) * 512 + (long)(kt) * 32) * 2 + cb,              \
            (char*)sB[buf] + c1 * 1024);                                    \
  } while (0)

  STAGE_QKV(0, 0);
  STAGE_QKV(1, 1);

  for (int kt = 0; kt < 16; ++kt) {
    int cur = kt % 3;
    if (kt < 15) vmwait<4>(); else vmwait<0>();
    BARX();
    bf16x8 af[4], bf[4];
#pragma unroll
    for (int m = 0; m < 4; ++m)
      af[m] = *(const bf16x8*)&sA[cur][(wm + m * 16 + fr) * 32 + fo * 8];
#pragma unroll
    for (int n = 0; n < 4; ++n)
      bf[n] = *(const bf16x8*)&sB[cur][(wn + n * 16 + fr) * 32 + fo * 8];
    if (kt < 14) STAGE_QKV((kt + 2) % 3, kt + 2);
#pragma unroll
    for (int m = 0; m < 4; ++m)
#pragma unroll
      for (int n = 0; n < 4; ++n)
        acc[m][n] = __builtin_amdgcn_mfma_f32_16x16x32_bf16(af[m], bf[n], acc[m][n], 0, 0, 0);
    lgkm0();  // my frag reads of buf[cur] executed -> safe to overwrite after next barrier
  }
#undef STAGE_QKV

  int rbase = m0 + wm + fo * 4, cbase = n0 + wn + fr;
#pragma unroll
  for (int n = 0; n < 4; ++n) {
    int col = cbase + n * 16;
    float bn = bias[col];
#pragma unroll
    for (int m = 0; m < 4; ++m) {
      int row = rbase + m * 16;
#pragma unroll
      for (int q = 0; q < 4; ++q)
        C[(size_t)(row + q) * NQKV + col] = f2bf(acc[m][n][q] + bn);
    }
  }
}

// ========== O GEMM: 64x128, BK=32, TRIPLE-buffer counted-vmcnt pipeline ==========
__global__ __launch_bounds__(256) void gemm_o(
    const u16* __restrict__ A, const u16* __restrict__ B,
    const float* __restrict__ bias, float* __restrict__ C) {
  __shared__ u16 sA[3][64 * 32], sB[3][128 * 32];  // 36KB
  int t = threadIdx.x, w = t >> 6, lane = t & 63;
  int bid = blockIdx.y * 4 + blockIdx.x;
  int swz = (bid & 7) * 64 + (bid >> 3);
  long m0 = (long)(swz / 4) * 64, n0 = (long)(swz % 4) * 128;
  int wn = w * 32;
  int fr = lane & 15, fo = lane >> 4;
  int rl = lane >> 2, cb = (lane & 3) * 16;
  const char* Ab = (const char*)A;
  const char* Bb = (const char*)B;

  f32x4 acc[4][2] = {};

  // 3 VMEM insts per thread per stage (A x1, B x2)
#define STAGE_O(buf, kt)                                                    \
  do {                                                                      \
    int ra = w * 16 + rl;                                                   \
    stage16(Ab + ((m0 + ra) * 512 + (long)(kt) * 32) * 2 + cb,              \
            (char*)sA[buf] + w * 1024);                                     \
    int c0 = w, c1 = w + 4;                                                 \
    int r0 = c0 * 16 + rl, r1 = c1 * 16 + rl;                               \
    stage16(Bb + ((n0 + r0) * 512 + (long)(kt) * 32) * 2 + cb,              \
            (char*)sB[buf] + c0 * 1024);                                    \
    stage16(Bb + ((n0 + r1) * 512 + (long)(kt) * 32) * 2 + cb,              \
            (char*)sB[buf] + c1 * 1024);                                    \
  } while (0)

  STAGE_O(0, 0);
  STAGE_O(1, 1);

  for (int kt = 0; kt < 16; ++kt) {
    int cur = kt % 3;
    if (kt < 15) vmwait<3>(); else vmwait<0>();
    BARX();
    bf16x8 af[4], bf[2];
#pragma unroll
    for (int m = 0; m < 4; ++m)
      af[m] = *(const bf16x8*)&sA[cur][(m * 16 + fr) * 32 + fo * 8];
#pragma unroll
    for (int n = 0; n < 2; ++n)
      bf[n] = *(const bf16x8*)&sB[cur][(wn + n * 16 + fr) * 32 + fo * 8];
    if (kt < 14) STAGE_O((kt + 2) % 3, kt + 2);
#pragma unroll
    for (int m = 0; m < 4; ++m)
#pragma unroll
      for (int n = 0; n < 2; ++n)
        acc[m][n] = __builtin_amdgcn_mfma_f32_16x16x32_bf16(af[m], bf[n], acc[m][n], 0, 0, 0);
    lgkm0();
  }
#undef STAGE_O

  int rbase = m0 + fo * 4, cbase = n0 + wn + fr;
#pragma unroll
  for (int n = 0; n < 2; ++n) {
    int col = cbase + n * 16;
    float bn = bias[col];
#pragma unroll
    for (int m = 0; m < 4; ++m) {
      int row = rbase + m * 16;
#pragma unroll
      for (int q = 0; q < 4; ++q)
        C[(size_t)(row + q) * 512 + col] = acc[m][n][q] + bn;
    }
  }
}

// ================= banded flash-attention on MFMA (r10-identical) =================
#define ATTN_LDS 73216

__global__ __launch_bounds__(256) void attn_mfma(const u16* __restrict__ QKV,
                                                 u16* __restrict__ AOh) {
  extern __shared__ char lds[];
  u16* sQ = (u16*)lds;                     // [128][72]
  u16* sK = (u16*)(lds + 18432);           // [160][72]
  u16* sVT = (u16*)(lds + 41472);          // [64][176]
  int t = threadIdx.x, w = t >> 6, lane = t & 63;
  u16* sP = (u16*)(lds + 64000 + w * 2304);  // [16][72] wave-private

  int blk = blockIdx.x;
  int tile = blk & 15, h = (blk >> 4) & 7, b = blk >> 7;
  int l0 = tile * 128;
  const u16* base = QKV + (size_t)b * L_SEQ * NQKV + h * D_K;

#pragma unroll
  for (int i = 0; i < 4; ++i) {
    int task = t + i * 256;
    int row = task >> 3, oct = task & 7;
    u16x8 g = *(const u16x8*)(base + (size_t)(l0 + row) * NQKV + oct * 8);
    *(u16x8*)(sQ + row * 72 + oct * 8) = g;
  }
#pragma unroll
  for (int i = 0; i < 5; ++i) {
    int task = t + i * 256;
    int row = task >> 3, oct = task & 7;
    int l = min(max(l0 - 16 + row, 0), L_SEQ - 1);
    u16x8 g = *(const u16x8*)(base + (size_t)l * NQKV + 512 + oct * 8);
    *(u16x8*)(sK + row * 72 + oct * 8) = g;
  }
#pragma unroll
  for (int i = 0; i < 5; ++i) {
    int task = t + i * 256;
    int kv = task >> 3, oct = task & 7;
    int l = min(max(l0 - 16 + kv, 0), L_SEQ - 1);
    u16x8 g = *(const u16x8*)(base + (size_t)l * NQKV + 1024 + oct * 8);
#pragma unroll
    for (int e = 0; e < 8; ++e)
      sVT[(oct * 8 + e) * 176 + kv] = g[e];
  }
  if (t < 128) {
    u16x8 z = {};
    *(u16x8*)(sVT + (t >> 1) * 176 + 160 + (t & 1) * 8) = z;
  }
  if (lane < 32) {
    u16x8 z = {};
    *(u16x8*)(sP + (lane >> 1) * 72 + 48 + (lane & 1) * 8) = z;
  }
  __syncthreads();

  int fr = lane & 15, fo = lane >> 4;

  for (int qi = 0; qi < 2; ++qi) {
    if (qi) __syncthreads();
    int qt = w * 2 + qi;

    bf16x8 Aq[2];
#pragma unroll
    for (int ks = 0; ks < 2; ++ks)
      Aq[ks] = *(const bf16x8*)(sQ + (qt * 16 + fr) * 72 + ks * 32 + fo * 8);

    f32x4 sc[3] = {};
#pragma unroll
    for (int kt = 0; kt < 3; ++kt)
#pragma unroll
      for (int ks = 0; ks < 2; ++ks) {
        bf16x8 Bk = *(const bf16x8*)(sK + (qt * 16 + kt * 16 + fr) * 72 + ks * 32 + fo * 8);
        sc[kt] = __builtin_amdgcn_mfma_f32_16x16x32_bf16(Aq[ks], Bk, sc[kt], 0, 0, 0);
      }

    float pj[3][4], mj[4], rj[4];
#pragma unroll
    for (int j = 0; j < 4; ++j) {
      int irow = l0 + qt * 16 + fo * 4 + j;
      float mloc = -1.0e30f;
#pragma unroll
      for (int kt = 0; kt < 3; ++kt) {
        int jcol = l0 - 16 + qt * 16 + kt * 16 + fr;
        float sv = fminf(fmaxf(sc[kt][j] * 0.125f, -10000.f), 10000.f);
        int dd = irow - jcol;
        bool ok = (dd <= WIN) && (dd >= -WIN) && (jcol >= 0) && (jcol < L_SEQ);
        sv = ok ? sv : -1.0e30f;
        pj[kt][j] = sv;
        mloc = fmaxf(mloc, sv);
      }
      mj[j] = mloc;
    }
#pragma unroll
    for (int st = 1; st <= 8; st <<= 1)
#pragma unroll
      for (int j = 0; j < 4; ++j)
        mj[j] = fmaxf(mj[j], __shfl_xor(mj[j], st));
#pragma unroll
    for (int j = 0; j < 4; ++j) {
      float r = 0.f;
#pragma unroll
      for (int kt = 0; kt < 3; ++kt) {
        float e = (pj[kt][j] > -1.0e29f) ? __expf(pj[kt][j] - mj[j]) : 0.f;
        pj[kt][j] = e;
        r += e;
      }
      rj[j] = r;
    }
#pragma unroll
    for (int st = 1; st <= 8; st <<= 1)
#pragma unroll
      for (int j = 0; j < 4; ++j)
        rj[j] += __shfl_xor(rj[j], st);
#pragma unroll
    for (int j = 0; j < 4; ++j) rj[j] = 1.f / rj[j];

#pragma unroll
    for (int kt = 0; kt < 3; ++kt)
#pragma unroll
      for (int j = 0; j < 4; ++j)
        sP[(fo * 4 + j) * 72 + kt * 16 + fr] = f2bf(pj[kt][j] * rj[j]);

    f32x4 oa[4] = {};
#pragma unroll
    for (int ks = 0; ks < 2; ++ks) {
      bf16x8 Ap = *(const bf16x8*)(sP + fr * 72 + ks * 32 + fo * 8);
#pragma unroll
      for (int nt = 0; nt < 4; ++nt) {
        bf16x8 Bv = *(const bf16x8*)(sVT + (nt * 16 + fr) * 176 + qt * 16 + ks * 32 + fo * 8);
        oa[nt] = __builtin_amdgcn_mfma_f32_16x16x32_bf16(Ap, Bv, oa[nt], 0, 0, 0);
      }
    }

#pragma unroll
    for (int nt = 0; nt < 4; ++nt)
#pragma unroll
      for (int j = 0; j < 4; ++j) {
        size_t row = (size_t)b * L_SEQ + l0 + qt * 16 + fo * 4 + j;
        AOh[row * D_MODEL + h * D_K + nt * 16 + fr] = f2bf(oa[nt][j]);
      }
  }
}

extern "C" void kernel_launch(void* const* d_in, const int* in_sizes, int n_in,
                              void* d_out, int out_size, void* d_ws, size_t ws_size,
                              hipStream_t stream) {
  const float* Q  = (const float*)d_in[0];
  const float* Wq = (const float*)d_in[1];
  const float* bq = (const float*)d_in[2];
  const float* Wk = (const float*)d_in[3];
  const float* bk = (const float*)d_in[4];
  const float* Wv = (const float*)d_in[5];
  const float* bv = (const float*)d_in[6];
  const float* Wo = (const float*)d_in[7];
  const float* bo = (const float*)d_in[8];
  float* out = (float*)d_out;

  char* p = (char*)d_ws;
  u16* Xh = (u16*)p;        p += (size_t)M_ROWS * 512 * 2;
  u16* Bqkv = (u16*)p;      p += (size_t)1536 * 512 * 2;
  u16* Bo = (u16*)p;        p += (size_t)512 * 512 * 2;
  float* bias_qkv = (float*)p; p += 1536 * 4;
  u16* QKV = (u16*)p;       p += (size_t)M_ROWS * 1536 * 2;
  u16* AOh = (u16*)p;       p += (size_t)M_ROWS * 512 * 2;

  hipFuncSetAttribute((const void*)attn_mfma,
                      hipFuncAttributeMaxDynamicSharedMemorySize, ATTN_LDS);

  hipLaunchKernelGGL(prep, dim3(4353), dim3(256), 0, stream,
                     Q, Wq, Wk, Wv, Wo, bq, bk, bv, Xh, Bqkv, Bo, bias_qkv);

  // QKV: 12 n-tiles x 64 m-tiles = 768 blocks
  gemm_qkv<<<dim3(12, 64), dim3(256), 0, stream>>>(Xh, Bqkv, bias_qkv, QKV);

  // attn: (b, h, tile) = 4*8*16 = 512 blocks (2/CU)
  hipLaunchKernelGGL(attn_mfma, dim3(512), dim3(256), ATTN_LDS, stream, QKV, AOh);

  // O: 4 n-tiles x 128 m-tiles = 512 blocks
  gemm_o<<<dim3(4, 128), dim3(256), 0, stream>>>(AOh, Bo, bo, out);
}